// Round 4
// baseline (423.403 us; speedup 1.0000x reference)
//
#include <hip/hip_runtime.h>
#include <hip/hip_cooperative_groups.h>
#include <math.h>

namespace cg = cooperative_groups;

#define NROWS 262144
#define NPART 1024
#define MAXTIES 256
#define H1BINS 4096
#define H2BINS 4096
#define H3BINS 256
typedef unsigned int uint;

struct Accum {
  double kl_part[NPART];
  double tls_part[NPART];
  double clean_part[NPART];
  double corr_part[NPART];
  double cnt_part[NPART];
  uint tie_cnt;
  uint tie_idx[MAXTIES];
};

// ============ DPP 16-lane reductions (VALU-speed, no ds_swizzle latency) ============
// quad_perm xor1 = 0xB1, xor2 = 0x4E; row_ror:4 = 0x124, row_ror:8 = 0x128.
// Stages: quad-xor1, quad-xor2 (each lane has its quad total), ror4, ror8
// (each lane combines the other three quads) -> all 16 lanes hold the full result.
template <int C> __device__ __forceinline__ float dppf(float x) {
  return __int_as_float(__builtin_amdgcn_update_dpp(0, __float_as_int(x), C, 0xF, 0xF, true));
}
template <int C> __device__ __forceinline__ int dppi(int x) {
  return __builtin_amdgcn_update_dpp(0, x, C, 0xF, 0xF, true);
}
__device__ __forceinline__ float rsum16(float x) {
  x += dppf<0xB1>(x);
  x += dppf<0x4E>(x);
  x += dppf<0x124>(x);
  x += dppf<0x128>(x);
  return x;
}
#define RMAX_STAGE(CTRL)                                  \
  { float om = dppf<CTRL>(m); int oi = dppi<CTRL>(i);     \
    if (om > m || (om == m && oi < i)) { m = om; i = oi; } }
__device__ __forceinline__ void rmax16(float& m, int& i) {
  RMAX_STAGE(0xB1)
  RMAX_STAGE(0x4E)
  RMAX_STAGE(0x124)
  RMAX_STAGE(0x128)
}

// ============ parallel bin-select helpers ============
__device__ __forceinline__ void select256(uint h, uint k, uint* wsum, uint* binrem) {
  int t = threadIdx.x, l = t & 63, w = t >> 6;
  uint incl = h;
#pragma unroll
  for (int d = 1; d < 64; d <<= 1) {
    uint o = __shfl_up(incl, d, 64);
    incl += (l >= d) ? o : 0u;
  }
  if (l == 63) wsum[w] = incl;
  __syncthreads();
  uint off = 0;
#pragma unroll
  for (int i = 0; i < 3; i++) off += (i < w) ? wsum[i] : 0u;
  incl += off;
  uint excl = incl - h;
  if (incl >= k && excl < k) { binrem[0] = (uint)t; binrem[1] = k - excl; }
  __syncthreads();
}

__device__ __forceinline__ void hist_select(const uint* __restrict__ hist, int L, uint k,
                                            uint* wsum, uint* binrem,
                                            uint* out_bin, uint* out_rem) {
  int t = threadIdx.x;
  if (L == 4096) {
    const uint4* hp = reinterpret_cast<const uint4*>(hist + t * 16);
    uint4 v0 = hp[0], v1 = hp[1], v2 = hp[2], v3 = hp[3];
    uint h = v0.x + v0.y + v0.z + v0.w + v1.x + v1.y + v1.z + v1.w
           + v2.x + v2.y + v2.z + v2.w + v3.x + v3.y + v3.z + v3.w;
    select256(h, k, wsum, binrem);
    uint chunk = binrem[0], rem1 = binrem[1];
    __syncthreads();
    uint h2 = (t < 16) ? hist[chunk * 16 + t] : 0u;
    select256(h2, rem1, wsum, binrem);
    *out_bin = chunk * 16 + binrem[0];
    *out_rem = binrem[1];
    __syncthreads();
  } else {
    uint h = hist[t];
    select256(h, k, wsum, binrem);
    *out_bin = binrem[0];
    *out_rem = binrem[1];
    __syncthreads();
  }
}

__device__ __forceinline__ uint calc_nr(int ep) {
  double fr = 0.005 * (double)ep; if (fr > 0.5) fr = 0.5;
  double rr = 1.0 - fr;           if (rr < 0.5) rr = 0.5;
  return (uint)(rr * (double)NROWS);
}

__device__ __forceinline__ double block_sum_d(double v, double* s) {
#pragma unroll
  for (int msk = 1; msk < 64; msk <<= 1) v += __shfl_xor(v, msk, 64);
  int wid = threadIdx.x >> 6, lane = threadIdx.x & 63;
  __syncthreads();
  if (lane == 0) s[wid] = v;
  __syncthreads();
  return s[0] + s[1] + s[2] + s[3];
}

// ============ K1: per-row stats, 16 lanes/row, 8 rows/wave, DPP reductions ============
__device__ __forceinline__ void process_group(
    const float av[8], const float bv[8], int t, int row, int seg, int base,
    const float* __restrict__ y1, const float* __restrict__ y2,
    float* __restrict__ tl, float* __restrict__ corr, unsigned char* __restrict__ mask,
    float* skl, float* stt, int slot) {
  float m1 = av[0]; int i1 = 0;
#pragma unroll
  for (int j = 1; j < 8; j++) { if (av[j] > m1) { m1 = av[j]; i1 = j; } }
  i1 += base;
  rmax16(m1, i1);
  float m2 = bv[0]; int i2 = 0;
#pragma unroll
  for (int j = 1; j < 8; j++) { if (bv[j] > m2) { m2 = bv[j]; i2 = j; } }
  i2 += base;
  rmax16(m2, i2);

  float e1[8], e2[8];
  float z1 = 0.f, z2 = 0.f;
#pragma unroll
  for (int j = 0; j < 8; j++) { e1[j] = __expf(av[j] - m1); z1 += e1[j]; }
#pragma unroll
  for (int j = 0; j < 8; j++) { e2[j] = __expf(bv[j] - m2); z2 += e2[j]; }
  z1 = rsum16(z1);
  z2 = rsum16(z2);
  float logZ1 = m1 + __logf(z1), logZ2 = m2 + __logf(z2);
  float rz1 = 1.f / z1, rz2 = 1.f / z2;
  float dZ = logZ1 - logZ2;
  float kl = 0.f;
#pragma unroll
  for (int j = 0; j < 8; j++)
    kl += (e1[j] * rz1 - e2[j] * rz2) * ((av[j] - bv[j]) - dZ);
  kl = rsum16(kl);

  if (seg == 0) {
    // direct cache-hot loads (lines just fetched by this wave -> L1 resident)
    const float* r1p = y1 + (size_t)row * 128;
    const float* r2p = y2 + (size_t)row * 128;
    float y1t = r1p[t], y2t = r2p[t], y2pl = r2p[i1];
    float total = (logZ1 - y1t) + (logZ2 - y2t);   // >= 0
    float prod = rz1 * rz2;                        // conf1*conf2
    float corrv = sqrtf(prod) * ((logZ1 - m1) + (logZ2 - y2pl));
    tl[row] = total;
    corr[row] = corrv;
    mask[row] = (unsigned char)((i1 == i2) && (prod > 0.5f));
    skl[slot] = kl;
    stt[slot] = total;
  }
}

__global__ __launch_bounds__(256) void k_rows(
    const float* __restrict__ y1, const float* __restrict__ y2,
    const int* __restrict__ tgt,
    float* __restrict__ tl, float* __restrict__ corr, unsigned char* __restrict__ mask,
    Accum* __restrict__ acc) {
  const int tid = threadIdx.x;
  const int w = tid >> 6, l = tid & 63;
  const int wb = blockIdx.x * 32 + w * 8;
  const int seg = l & 15, base = seg * 8, sub = l >> 4;

  const float4* q1 = reinterpret_cast<const float4*>(y1 + (size_t)wb * 128) + 2 * l;
  const float4* q2 = reinterpret_cast<const float4*>(y2 + (size_t)wb * 128) + 2 * l;
  float4 a00 = q1[0],   a01 = q1[1];
  float4 a10 = q1[128], a11 = q1[129];
  float4 b00 = q2[0],   b01 = q2[1];
  float4 b10 = q2[128], b11 = q2[129];
  int r0 = wb + sub, r1 = wb + 4 + sub;
  int t0 = tgt[r0], t1 = tgt[r1];

  __shared__ float skl[32], stt[32];
  float av0[8] = {a00.x,a00.y,a00.z,a00.w,a01.x,a01.y,a01.z,a01.w};
  float bv0[8] = {b00.x,b00.y,b00.z,b00.w,b01.x,b01.y,b01.z,b01.w};
  float av1[8] = {a10.x,a10.y,a10.z,a10.w,a11.x,a11.y,a11.z,a11.w};
  float bv1[8] = {b10.x,b10.y,b10.z,b10.w,b11.x,b11.y,b11.z,b11.w};
  process_group(av0, bv0, t0, r0, seg, base, y1, y2, tl, corr, mask, skl, stt, w * 8 + sub);
  process_group(av1, bv1, t1, r1, seg, base, y1, y2, tl, corr, mask, skl, stt, w * 8 + 4 + sub);
  __syncthreads();
  if (tid == 0) {
    double sk = 0.0, st = 0.0;
#pragma unroll
    for (int i = 0; i < 32; i++) { sk += (double)skl[i]; st += (double)stt[i]; }
    int slot = blockIdx.x & (NPART - 1);
    atomicAdd(&acc->kl_part[slot], sk);
    atomicAdd(&acc->tls_part[slot], st);
  }
}

// ============ K2: cooperative select/partition/finalize (replaces 5 kernels) ============
// 256 blocks x 256 threads, 1 block/CU, 4 rows/thread held in registers across phases.
__global__ __launch_bounds__(256) void k_select(
    const float* __restrict__ tl, const float* __restrict__ corr,
    const unsigned char* __restrict__ mask,
    uint* __restrict__ hist1, uint* __restrict__ hist2, uint* __restrict__ hist3,
    const int* __restrict__ ep, Accum* __restrict__ acc, float* __restrict__ out) {
  cg::grid_group grid = cg::this_grid();
  __shared__ uint lh[H1BINS];
  __shared__ uint wsum[4], binrem[2];
  __shared__ double sred[4];
  const int t = threadIdx.x, b = blockIdx.x;
  const int idx = b * 256 + t;
  const uint4 kk = reinterpret_cast<const uint4*>(tl)[idx];   // 4 row keys, reused all phases

  // ---- phase 1: level-1 histogram (top 12 bits), LDS-privatized ----
  for (int j = t; j < H1BINS; j += 256) lh[j] = 0;
  __syncthreads();
  atomicAdd(&lh[kk.x >> 20], 1u);
  atomicAdd(&lh[kk.y >> 20], 1u);
  atomicAdd(&lh[kk.z >> 20], 1u);
  atomicAdd(&lh[kk.w >> 20], 1u);
  __syncthreads();
  for (int j = t; j < H1BINS; j += 256) {
    uint v = lh[j];
    if (v) atomicAdd(&hist1[j], v);
  }
  grid.sync();

  // ---- phase 2: select B1, build level-2 histogram (bits 19:8) ----
  uint nr = calc_nr(ep[0]);
  uint B1, r1;
  hist_select(hist1, H1BINS, nr, wsum, binrem, &B1, &r1);
  if ((kk.x >> 20) == B1) atomicAdd(&hist2[(kk.x >> 8) & 0xFFFu], 1u);
  if ((kk.y >> 20) == B1) atomicAdd(&hist2[(kk.y >> 8) & 0xFFFu], 1u);
  if ((kk.z >> 20) == B1) atomicAdd(&hist2[(kk.z >> 8) & 0xFFFu], 1u);
  if ((kk.w >> 20) == B1) atomicAdd(&hist2[(kk.w >> 8) & 0xFFFu], 1u);
  grid.sync();

  // ---- phase 3: select B2, build level-3 histogram (bits 7:0) ----
  uint B2, r2;
  hist_select(hist2, H2BINS, r1, wsum, binrem, &B2, &r2);
  uint pref = (B1 << 12) | B2;
  if ((kk.x >> 8) == pref) atomicAdd(&hist3[kk.x & 0xFFu], 1u);
  if ((kk.y >> 8) == pref) atomicAdd(&hist3[kk.y & 0xFFu], 1u);
  if ((kk.z >> 8) == pref) atomicAdd(&hist3[kk.z & 0xFFu], 1u);
  if ((kk.w >> 8) == pref) atomicAdd(&hist3[kk.w & 0xFFu], 1u);
  grid.sync();

  // ---- phase 4: select B3 -> T, partition ----
  uint B3, needed;
  hist_select(hist3, H3BINS, r2, wsum, binrem, &B3, &needed);
  uint T = (B1 << 20) | (B2 << 8) | B3;

  float4 cv = reinterpret_cast<const float4*>(corr)[idx];
  uint mb = reinterpret_cast<const uint*>(mask)[idx];
  uint kks[4] = {kk.x, kk.y, kk.z, kk.w};
  float cvs[4] = {cv.x, cv.y, cv.z, cv.w};
  double cl = 0.0, co = 0.0, cn = 0.0;
#pragma unroll
  for (int j = 0; j < 4; j++) {
    uint key = kks[j];
    if (key < T) {
      cl += (double)__uint_as_float(key);
    } else if (key == T) {
      uint p = atomicAdd(&acc->tie_cnt, 1u);
      if (p < MAXTIES) acc->tie_idx[p] = (uint)(idx * 4 + j);
    } else if ((mb >> (8 * j)) & 0xFFu) {
      co += (double)cvs[j]; cn += 1.0;
    }
  }
  double scl = block_sum_d(cl, sred);
  double sco = block_sum_d(co, sred);
  double scn = block_sum_d(cn, sred);
  if (t == 0) {
    acc->clean_part[b] = scl;
    acc->corr_part[b]  = sco;
    acc->cnt_part[b]   = scn;
  }
  __threadfence();
  grid.sync();

  // ---- phase 5: block 0 finalizes ----
  if (b != 0) return;
  double kl = 0, tls = 0, cl2 = 0, co2 = 0, cn2 = 0;
  for (int i = t; i < NPART; i += 256) {
    kl  += acc->kl_part[i];
    tls += acc->tls_part[i];
    cl2 += acc->clean_part[i];
    co2 += acc->corr_part[i];
    cn2 += acc->cnt_part[i];
  }
  kl  = block_sum_d(kl,  sred);
  tls = block_sum_d(tls, sred);
  cl2 = block_sum_d(cl2, sred);
  co2 = block_sum_d(co2, sred);
  cn2 = block_sum_d(cn2, sred);

  if (t == 0) {
    int e = ep[0];
    if (e == 0) { out[0] = (float)(tls / (double)NROWS); return; }

    uint m = acc->tie_cnt; if (m > MAXTIES) m = MAXTIES;
    float Tval = __uint_as_float(T);
    cl2 += (double)Tval * (double)needed;    // ties going clean (identical value)
    if (m > needed) {
      // stable argsort tie-break by row index
      for (int a2 = 1; a2 < (int)m; a2++) {
        uint v = acc->tie_idx[a2];
        int b2 = a2 - 1;
        while (b2 >= 0 && acc->tie_idx[b2] > v) { acc->tie_idx[b2 + 1] = acc->tie_idx[b2]; b2--; }
        acc->tie_idx[b2 + 1] = v;
      }
      for (uint j = needed; j < m; j++) {
        uint idx2 = acc->tie_idx[j];
        if (mask[idx2]) { co2 += (double)corr[idx2]; cn2 += 1.0; }
      }
    }
    double clean_loss = cl2 / (double)nr;
    double corr_mean = (cn2 > 0.5) ? (co2 / cn2) : 0.0;
    double kl_mean = kl / (double)NROWS;
    out[0] = (float)(clean_loss + corr_mean + 0.1 * kl_mean);
  }
}

extern "C" void kernel_launch(void* const* d_in, const int* in_sizes, int n_in,
                              void* d_out, int out_size, void* d_ws, size_t ws_size,
                              hipStream_t stream) {
  const float* y1 = (const float*)d_in[0];
  const float* y2 = (const float*)d_in[1];
  const int* tgt = (const int*)d_in[2];
  const int* epoch = (const int*)d_in[3];
  float* out = (float*)d_out;

  float* tl = (float*)d_ws;                                   // N floats
  float* corrv = tl + NROWS;                                  // N floats
  unsigned char* mask = (unsigned char*)(corrv + NROWS);      // N bytes
  uint* hist1 = (uint*)(mask + NROWS);                        // 4096
  uint* hist2 = hist1 + H1BINS;                               // 4096
  uint* hist3 = hist2 + H2BINS;                               // 256
  Accum* acc = (Accum*)(hist3 + H3BINS);

  size_t zbytes = (size_t)(H1BINS + H2BINS + H3BINS) * 4 + sizeof(Accum);
  hipMemsetAsync(hist1, 0, zbytes, stream);

  k_rows<<<NROWS / 32, 256, 0, stream>>>(y1, y2, tgt, tl, corrv, mask, acc);

  void* args[] = {(void*)&tl, (void*)&corrv, (void*)&mask, (void*)&hist1,
                  (void*)&hist2, (void*)&hist3, (void*)&epoch, (void*)&acc, (void*)&out};
  hipLaunchCooperativeKernel((void*)k_select, dim3(256), dim3(256), args, 0, stream);
}